// Round 1
// baseline (458.018 us; speedup 1.0000x reference)
//
#include <hip/hip_runtime.h>
#include <hip/hip_bf16.h>

// ---------------------------------------------------------------------------
// MultiheadAttentionZero: Q/K/V proj + RoPE + masked softmax attn + out proj
// B=4 T=S=2048 DIM=1024 H=16 Dh=64.  All matmuls via mfma_f32_16x16x32_bf16.
// ---------------------------------------------------------------------------

typedef __bf16 bf16;
typedef __bf16 bf16x8 __attribute__((ext_vector_type(8)));
typedef __bf16 bf16x4 __attribute__((ext_vector_type(4)));
typedef float  f32x4  __attribute__((ext_vector_type(4)));

#define NB   4
#define NT   2048
#define NS   2048
#define NH   16
#define HD   64
// scale = Dh^-0.5 * log2(e)  (softmax done in log2 domain; exp2f -> v_exp_f32)
#define SCL  0.18033688011112043f

__device__ __forceinline__ void gload16(const void* g, void* l) {
  // async global->LDS, 16B/lane; LDS dest = wave-uniform base + lane*16
  __builtin_amdgcn_global_load_lds((const __attribute__((address_space(1))) void*)g,
                                   (__attribute__((address_space(3))) void*)l, 16, 0, 0);
}

__device__ __forceinline__ f32x4 mfma16(bf16x8 a, bf16x8 b, f32x4 c) {
  return __builtin_amdgcn_mfma_f32_16x16x32_bf16(a, b, c, 0, 0, 0);
}

// ---------------------------------------------------------------------------
// Prep 1: f32 -> bf16 conversion of [Wq|Wk|Wv|Wproj], q_x, kv_x   (vector x4)
// ---------------------------------------------------------------------------
__global__ void k_convert(const float* __restrict__ qx, const float* __restrict__ kvx,
                          const float* __restrict__ Wq, const float* __restrict__ Wk,
                          const float* __restrict__ Wv, const float* __restrict__ Wp,
                          bf16* __restrict__ wbf, bf16* __restrict__ qxbf,
                          bf16* __restrict__ kvxbf)
{
  const long total = 4194304L + 8388608L + 8388608L;   // 4 weights + qx + kvx
  for (long v = (long)blockIdx.x * blockDim.x + threadIdx.x; v * 4 < total;
       v += (long)gridDim.x * blockDim.x) {
    long e0 = v * 4;
    const float* src; bf16* dst;
    if (e0 < 4194304L) {
      int widx = (int)(e0 >> 20);
      const float* wsrc = (widx == 0) ? Wq : (widx == 1) ? Wk : (widx == 2) ? Wv : Wp;
      src = wsrc + (e0 & 1048575); dst = wbf + e0;
    } else if (e0 < 12582912L) {
      src = qx + (e0 - 4194304L); dst = qxbf + (e0 - 4194304L);
    } else {
      src = kvx + (e0 - 12582912L); dst = kvxbf + (e0 - 12582912L);
    }
    float4 f = *(const float4*)src;
    bf16x4 o = {(bf16)f.x, (bf16)f.y, (bf16)f.z, (bf16)f.w};
    *(bf16x4*)dst = o;
  }
}

// ---------------------------------------------------------------------------
// Prep 2: cos/sin tables for RoPE (float2 {cos,sin}) + mask -> additive bias
// ---------------------------------------------------------------------------
__global__ void k_tables(const float* __restrict__ fq, const float* __restrict__ fkv,
                         const int* __restrict__ mask,
                         float2* __restrict__ csq, float2* __restrict__ cskv,
                         float* __restrict__ bias)
{
  int i = blockIdx.x * blockDim.x + threadIdx.x;
  if (i < 65536) {                       // 2048*32
    float s, c; sincosf(fq[i], &s, &c); csq[i] = make_float2(c, s);
  } else if (i < 131072) {
    int j = i - 65536;
    float s, c; sincosf(fkv[j], &s, &c); cskv[j] = make_float2(c, s);
  } else if (i < 139264) {               // + B*S
    int j = i - 131072;
    bias[j] = mask[j] ? 0.0f : -1.0e9f;
  }
}

// ---------------------------------------------------------------------------
// GEMM C = A(MxK) * W(NxK)^T, 128x128 tile, BK=32, 4 waves (2x2), m97-style.
// EPI=0: QKV (blockIdx.z = 0/1/2 -> Q+rope / K+rope / V^T)
// EPI=1: out proj, f32 output
// ---------------------------------------------------------------------------
template<int EPI>
__global__ __launch_bounds__(256) void k_gemm(
    const bf16* __restrict__ A0, const bf16* __restrict__ A1,
    const bf16* __restrict__ wbase,
    bf16* __restrict__ Qb, bf16* __restrict__ Kb, bf16* __restrict__ Vtb,
    float* __restrict__ Of,
    const float2* __restrict__ csq, const float2* __restrict__ cskv)
{
  __shared__ bf16 As[128 * 32];
  __shared__ bf16 Bs[128 * 32];
  const int z  = (EPI == 0) ? blockIdx.z : 0;
  const bf16* A = (EPI == 1) ? A0 : ((z == 0) ? A0 : A1);
  const bf16* W = wbase + (size_t)z * 1048576;
  const int m0 = blockIdx.x * 128, n0 = blockIdx.y * 128;
  const int tid = threadIdx.x, lane = tid & 63, w = tid >> 6;
  const int g = lane >> 4, c = lane & 15;
  const int wr = w >> 1, wc = w & 1;

  f32x4 acc[4][4];
#pragma unroll
  for (int i = 0; i < 4; ++i)
#pragma unroll
    for (int j = 0; j < 4; ++j) acc[i][j] = 0.0f;

  // staging: wave w stages 1KB chunks 2w,2w+1 of each 8KB tile (16 rows each)
  const bf16* gA = A + (size_t)(m0 + w * 32 + (lane >> 2)) * 1024 + (lane & 3) * 8;
  const bf16* gB = W + (size_t)(n0 + w * 32 + (lane >> 2)) * 1024 + (lane & 3) * 8;
  bf16* lA = As + w * 1024;
  bf16* lB = Bs + w * 1024;

  for (int k0 = 0; k0 < 1024; k0 += 32) {
    __syncthreads();
    gload16(gA, lA);               gload16(gA + 16 * 1024, lA + 512);
    gload16(gB, lB);               gload16(gB + 16 * 1024, lB + 512);
    gA += 32; gB += 32;
    __syncthreads();

    bf16x8 af[4], bfr[4];
#pragma unroll
    for (int mi = 0; mi < 4; ++mi)
      af[mi] = *(const bf16x8*)(As + (wr * 64 + mi * 16 + c) * 32 + g * 8);
#pragma unroll
    for (int ni = 0; ni < 4; ++ni)
      bfr[ni] = *(const bf16x8*)(Bs + (wc * 64 + ni * 16 + c) * 32 + g * 8);
#pragma unroll
    for (int mi = 0; mi < 4; ++mi)
#pragma unroll
      for (int ni = 0; ni < 4; ++ni)
        acc[mi][ni] = mfma16(af[mi], bfr[ni], acc[mi][ni]);
  }

  // C/D layout: col = lane&15, row = (lane>>4)*4 + reg  (m89-verified)
  if (EPI == 1) {
#pragma unroll
    for (int mi = 0; mi < 4; ++mi)
#pragma unroll
      for (int ni = 0; ni < 4; ++ni)
#pragma unroll
        for (int r = 0; r < 4; ++r) {
          int m = m0 + wr * 64 + mi * 16 + g * 4 + r;
          int n = n0 + wc * 64 + ni * 16 + c;
          Of[(size_t)m * 1024 + n] = acc[mi][ni][r];
        }
  } else if (z < 2) {
    // Q or K with fused RoPE: even/odd head-dim pairs are adjacent lanes
    const float2* cs = (z == 0) ? csq : cskv;
    bf16* Out = (z == 0) ? Qb : Kb;
#pragma unroll
    for (int mi = 0; mi < 4; ++mi)
#pragma unroll
      for (int ni = 0; ni < 4; ++ni)
#pragma unroll
        for (int r = 0; r < 4; ++r) {
          int m = m0 + wr * 64 + mi * 16 + g * 4 + r;
          int n = n0 + wc * 64 + ni * 16 + c;
          float v = acc[mi][ni][r];
          float p = __shfl_xor(v, 1);          // partner in the rope pair
          int t = m & 2047, b = m >> 11;
          int h = n >> 6, d = n & 63;
          float2 cv = cs[t * 32 + (d >> 1)];
          float rot = (d & 1) ? (v * cv.x + p * cv.y)    // odd:  xe*sin + xo*cos
                              : (v * cv.x - p * cv.y);   // even: xe*cos - xo*sin
          Out[((size_t)((b * 16 + h) * 2048 + t)) * 64 + d] = (bf16)rot;
        }
  } else {
    // V^T: [bh][d=64][s=2048] so attention PV B-operand is k-contiguous
#pragma unroll
    for (int mi = 0; mi < 4; ++mi)
#pragma unroll
      for (int ni = 0; ni < 4; ++ni) {
        int m = m0 + wr * 64 + mi * 16 + g * 4;   // 4 consecutive s (regs)
        int n = n0 + wc * 64 + ni * 16 + c;
        int b = m >> 11, sl = m & 2047;
        int h = n >> 6, d = n & 63;
        bf16x4 pk = {(bf16)acc[mi][ni][0], (bf16)acc[mi][ni][1],
                     (bf16)acc[mi][ni][2], (bf16)acc[mi][ni][3]};
        *(bf16x4*)(Vtb + ((size_t)((b * 16 + h) * 64 + d)) * 2048 + sl) = pk;
      }
  }
}

// ---------------------------------------------------------------------------
// Flash attention: 4 waves x 16 q-rows, KV tiles of 64, online softmax.
// K_lds [s][64d], V_lds = V^T [d][64s], P_lds [16t][64s] per wave — all rows
// are 128B so reads XOR-swizzle byte bits 4-6 with (row&7)<<4 (T2 pattern);
// staging pre-swizzles the *global* source so global_load_lds stays linear.
// ---------------------------------------------------------------------------
__global__ __launch_bounds__(256) void k_attn(
    const bf16* __restrict__ Qb, const bf16* __restrict__ Kb,
    const bf16* __restrict__ Vtb, const float* __restrict__ bias,
    bf16* __restrict__ Ob)
{
  __shared__ bf16 Ks[64 * 64];
  __shared__ bf16 Vs[64 * 64];
  __shared__ bf16 Ps[4 * 16 * 64];
  const int bh = blockIdx.y, b = bh >> 4, h = bh & 15;
  const int t0 = blockIdx.x * 64;
  const int tid = threadIdx.x, lane = tid & 63, w = tid >> 6;
  const int g = lane >> 4, c = lane & 15;

  // Q fragments (A-operand: row=lane&15, k = (lane>>4)*8 + i)
  bf16x8 qf[2];
  {
    const bf16* qp = Qb + ((size_t)bh * 2048 + t0 + w * 16 + c) * 64;
    qf[0] = *(const bf16x8*)(qp + g * 8);
    qf[1] = *(const bf16x8*)(qp + 32 + g * 8);
  }

  float mrun[4], lrun[4];
  f32x4 o[4];
#pragma unroll
  for (int r = 0; r < 4; ++r) { mrun[r] = -3.0e38f; lrun[r] = 0.0f; }
#pragma unroll
  for (int ni = 0; ni < 4; ++ni) o[ni] = 0.0f;

  // staging addresses (pre-swizzled source column)
  const int srow8 = lane >> 3;                     // row within 8-row chunk
  const int scol  = ((lane & 7) ^ srow8) * 8;      // inverse-swizzled elem off
  const bf16* gK = Kb  + ((size_t)bh * 2048 + w * 16 + srow8) * 64 + scol;
  const bf16* gV = Vtb + ((size_t)bh * 64 + w * 16 + srow8) * 2048 + scol;
  bf16* lK = Ks + w * 1024;
  bf16* lV = Vs + w * 1024;
  const float* bp = bias + b * 2048;

  for (int s0 = 0; s0 < 2048; s0 += 64) {
    __syncthreads();
    gload16(gK, lK);            gload16(gK + 512,      lK + 512);
    gload16(gV, lV);            gload16(gV + 8 * 2048, lV + 512);
    gK += 64 * 64; gV += 64;
    __syncthreads();

    // ---- QK^T: S[t][s], 64 keys = 4 col-subtiles, k=d in 2 steps of 32
    f32x4 sc[4];
#pragma unroll
    for (int st = 0; st < 4; ++st) sc[st] = 0.0f;
#pragma unroll
    for (int kd = 0; kd < 2; ++kd)
#pragma unroll
      for (int st = 0; st < 4; ++st) {
        int srow = st * 16 + c;
        bf16x8 kf = *(const bf16x8*)(Ks + srow * 64 + ((kd * 4 + g) ^ (srow & 7)) * 8);
        sc[st] = mfma16(qf[kd], kf, sc[st]);
      }

    // ---- scale + mask-bias (log2 domain)
    float sv[4][4];
#pragma unroll
    for (int st = 0; st < 4; ++st) {
      float bc = bp[s0 + st * 16 + c];
#pragma unroll
      for (int r = 0; r < 4; ++r) sv[st][r] = sc[st][r] * SCL + bc;
    }

    // ---- online softmax (rows live in 16-lane groups: shfl_xor 1/2/4/8)
    float mnew[4], corr[4], rsum[4];
#pragma unroll
    for (int r = 0; r < 4; ++r) {
      float mt = fmaxf(fmaxf(sv[0][r], sv[1][r]), fmaxf(sv[2][r], sv[3][r]));
      mt = fmaxf(mt, __shfl_xor(mt, 1));
      mt = fmaxf(mt, __shfl_xor(mt, 2));
      mt = fmaxf(mt, __shfl_xor(mt, 4));
      mt = fmaxf(mt, __shfl_xor(mt, 8));
      mnew[r] = fmaxf(mrun[r], mt);
      corr[r] = exp2f(mrun[r] - mnew[r]);
      mrun[r] = mnew[r];
      rsum[r] = 0.0f;
    }
    char* pbase = (char*)Ps + w * 2048;
#pragma unroll
    for (int st = 0; st < 4; ++st)
#pragma unroll
      for (int r = 0; r < 4; ++r) {
        float p = exp2f(sv[st][r] - mnew[r]);
        rsum[r] += p;
        int t = g * 4 + r;
        *(bf16*)(pbase + t * 128 + ((st * 32 + c * 2) ^ ((t & 7) << 4))) = (bf16)p;
      }
#pragma unroll
    for (int r = 0; r < 4; ++r) {
      float s = rsum[r];
      s += __shfl_xor(s, 1); s += __shfl_xor(s, 2);
      s += __shfl_xor(s, 4); s += __shfl_xor(s, 8);
      lrun[r] = lrun[r] * corr[r] + s;
    }
#pragma unroll
    for (int ni = 0; ni < 4; ++ni)
#pragma unroll
      for (int r = 0; r < 4; ++r) o[ni][r] *= corr[r];

    // P writes are wave-local: drain LDS then read fragments
    asm volatile("s_waitcnt lgkmcnt(0)" ::: "memory");
    __builtin_amdgcn_sched_barrier(0);

    // ---- PV: out[t][d] += P[t][s] * V[s][d], k=s in 2 steps of 32
#pragma unroll
    for (int ks = 0; ks < 2; ++ks) {
      bf16x8 pf = *(const bf16x8*)(pbase + c * 128 +
                                   ((((ks * 4 + g) << 4) ^ ((c & 7) << 4))));
#pragma unroll
      for (int ni = 0; ni < 4; ++ni) {
        int vrow = ni * 16 + c;
        bf16x8 vf = *(const bf16x8*)(Vs + vrow * 64 + (((ks * 4 + g) ^ (vrow & 7)) * 8));
        o[ni] = mfma16(pf, vf, o[ni]);
      }
    }
  }

  // epilogue: divide by l, write O [b][t][h*64+d] bf16
#pragma unroll
  for (int r = 0; r < 4; ++r) lrun[r] = 1.0f / lrun[r];
#pragma unroll
  for (int ni = 0; ni < 4; ++ni)
#pragma unroll
    for (int r = 0; r < 4; ++r) {
      int t = t0 + w * 16 + g * 4 + r;
      int d = ni * 16 + c;
      Ob[((size_t)(b * 2048 + t)) * 1024 + h * 64 + d] = (bf16)(o[ni][r] * lrun[r]);
    }
}

// ---------------------------------------------------------------------------
extern "C" void kernel_launch(void* const* d_in, const int* in_sizes, int n_in,
                              void* d_out, int out_size, void* d_ws, size_t ws_size,
                              hipStream_t stream)
{
  const float* qx  = (const float*)d_in[0];
  const float* kvx = (const float*)d_in[1];
  const float* fq  = (const float*)d_in[2];
  const float* fkv = (const float*)d_in[3];
  const int*  mask = (const int*)  d_in[4];
  const float* Wq  = (const float*)d_in[5];
  const float* Wk  = (const float*)d_in[6];
  const float* Wv  = (const float*)d_in[7];
  const float* Wp  = (const float*)d_in[8];

  char* ws = (char*)d_ws;
  bf16*   wbf   = (bf16*)(ws);                    //  8 MB: [Wq|Wk|Wv|Wproj] bf16
  bf16*   qxbf  = (bf16*)(ws + 8388608);          // 16 MB
  bf16*   kvxbf = (bf16*)(ws + 25165824);         // 16 MB
  bf16*   Qb    = (bf16*)(ws + 41943040);         // 16 MB  [bh][t][64]
  bf16*   Kb    = (bf16*)(ws + 58720256);         // 16 MB  [bh][s][64]
  bf16*   Vtb   = (bf16*)(ws + 75497472);         // 16 MB  [bh][64][s]
  bf16*   Ob    = (bf16*)(ws + 92274688);         // 16 MB  [b][t][1024]
  float2* csq   = (float2*)(ws + 109051904);      // 512 KB
  float2* cskv  = (float2*)(ws + 109576192);      // 512 KB
  float*  bias  = (float*)(ws + 110100480);       //  32 KB
  float*  out   = (float*)d_out;

  k_convert<<<4096, 256, 0, stream>>>(qx, kvx, Wq, Wk, Wv, Wp, wbf, qxbf, kvxbf);
  k_tables<<<544, 256, 0, stream>>>(fq, fkv, mask, csq, cskv, bias);
  k_gemm<0><<<dim3(64, 8, 3), 256, 0, stream>>>(qxbf, kvxbf, wbf,
                                                Qb, Kb, Vtb, nullptr, csq, cskv);
  k_attn<<<dim3(32, 64), 256, 0, stream>>>(Qb, Kb, Vtb, bias, Ob);
  k_gemm<1><<<dim3(64, 8, 1), 256, 0, stream>>>(Ob, nullptr, wbf + 3 * 1048576,
                                                nullptr, nullptr, nullptr, out, csq, cskv);
}

// Round 2
// 374.623 us; speedup vs baseline: 1.2226x; 1.2226x over previous
//
#include <hip/hip_runtime.h>
#include <hip/hip_bf16.h>

// ---------------------------------------------------------------------------
// MultiheadAttentionZero: Q/K/V proj + RoPE + masked softmax attn + out proj
// B=4 T=S=2048 DIM=1024 H=16 Dh=64.  All matmuls via mfma_f32_16x16x32_bf16.
// ---------------------------------------------------------------------------

typedef __bf16 bf16;
typedef __bf16 bf16x8 __attribute__((ext_vector_type(8)));
typedef __bf16 bf16x4 __attribute__((ext_vector_type(4)));
typedef float  f32x4  __attribute__((ext_vector_type(4)));

#define NB   4
#define NT   2048
#define NS   2048
#define NH   16
#define HD   64
// scale = Dh^-0.5 * log2(e)  (softmax done in log2 domain; exp2f -> v_exp_f32)
#define SCL  0.18033688011112043f

__device__ __forceinline__ void gload16(const void* g, void* l) {
  // async global->LDS, 16B/lane; LDS dest = wave-uniform base + lane*16
  __builtin_amdgcn_global_load_lds((const __attribute__((address_space(1))) void*)g,
                                   (__attribute__((address_space(3))) void*)l, 16, 0, 0);
}

__device__ __forceinline__ f32x4 mfma16(bf16x8 a, bf16x8 b, f32x4 c) {
  return __builtin_amdgcn_mfma_f32_16x16x32_bf16(a, b, c, 0, 0, 0);
}

// ---------------------------------------------------------------------------
// Prep 1: f32 -> bf16 conversion of [Wq|Wk|Wv|Wproj], q_x, kv_x   (vector x4)
// ---------------------------------------------------------------------------
__global__ void k_convert(const float* __restrict__ qx, const float* __restrict__ kvx,
                          const float* __restrict__ Wq, const float* __restrict__ Wk,
                          const float* __restrict__ Wv, const float* __restrict__ Wp,
                          bf16* __restrict__ wbf, bf16* __restrict__ qxbf,
                          bf16* __restrict__ kvxbf)
{
  const long total = 4194304L + 8388608L + 8388608L;   // 4 weights + qx + kvx
  for (long v = (long)blockIdx.x * blockDim.x + threadIdx.x; v * 4 < total;
       v += (long)gridDim.x * blockDim.x) {
    long e0 = v * 4;
    const float* src; bf16* dst;
    if (e0 < 4194304L) {
      int widx = (int)(e0 >> 20);
      const float* wsrc = (widx == 0) ? Wq : (widx == 1) ? Wk : (widx == 2) ? Wv : Wp;
      src = wsrc + (e0 & 1048575); dst = wbf + e0;
    } else if (e0 < 12582912L) {
      src = qx + (e0 - 4194304L); dst = qxbf + (e0 - 4194304L);
    } else {
      src = kvx + (e0 - 12582912L); dst = kvxbf + (e0 - 12582912L);
    }
    float4 f = *(const float4*)src;
    bf16x4 o = {(bf16)f.x, (bf16)f.y, (bf16)f.z, (bf16)f.w};
    *(bf16x4*)dst = o;
  }
}

// ---------------------------------------------------------------------------
// Prep 2: cos/sin tables for RoPE (float2 {cos,sin}) + mask -> additive bias
// ---------------------------------------------------------------------------
__global__ void k_tables(const float* __restrict__ fq, const float* __restrict__ fkv,
                         const int* __restrict__ mask,
                         float2* __restrict__ csq, float2* __restrict__ cskv,
                         float* __restrict__ bias)
{
  int i = blockIdx.x * blockDim.x + threadIdx.x;
  if (i < 65536) {                       // 2048*32
    float s, c; sincosf(fq[i], &s, &c); csq[i] = make_float2(c, s);
  } else if (i < 131072) {
    int j = i - 65536;
    float s, c; sincosf(fkv[j], &s, &c); cskv[j] = make_float2(c, s);
  } else if (i < 139264) {               // + B*S
    int j = i - 131072;
    bias[j] = mask[j] ? 0.0f : -1.0e9f;
  }
}

// ---------------------------------------------------------------------------
// GEMM C = A(MxK) * W(NxK)^T, 128x128 tile, BK=32, 4 waves (2x2), m97-style.
// EPI=0: QKV (blockIdx.z = 0/1/2 -> Q+rope / K+rope / V^T kappa-permuted)
// EPI=1: out proj, f32 output
// ---------------------------------------------------------------------------
template<int EPI>
__global__ __launch_bounds__(256) void k_gemm(
    const bf16* __restrict__ A0, const bf16* __restrict__ A1,
    const bf16* __restrict__ wbase,
    bf16* __restrict__ Qb, bf16* __restrict__ Kb, bf16* __restrict__ Vtb,
    float* __restrict__ Of,
    const float2* __restrict__ csq, const float2* __restrict__ cskv)
{
  __shared__ bf16 As[128 * 32];
  __shared__ bf16 Bs[128 * 32];
  const int z  = (EPI == 0) ? blockIdx.z : 0;
  const bf16* A = (EPI == 1) ? A0 : ((z == 0) ? A0 : A1);
  const bf16* W = wbase + (size_t)z * 1048576;
  const int m0 = blockIdx.x * 128, n0 = blockIdx.y * 128;
  const int tid = threadIdx.x, lane = tid & 63, w = tid >> 6;
  const int g = lane >> 4, c = lane & 15;
  const int wr = w >> 1, wc = w & 1;

  f32x4 acc[4][4];
#pragma unroll
  for (int i = 0; i < 4; ++i)
#pragma unroll
    for (int j = 0; j < 4; ++j) acc[i][j] = 0.0f;

  // staging: wave w stages 1KB chunks 2w,2w+1 of each 8KB tile (16 rows each)
  const bf16* gA = A + (size_t)(m0 + w * 32 + (lane >> 2)) * 1024 + (lane & 3) * 8;
  const bf16* gB = W + (size_t)(n0 + w * 32 + (lane >> 2)) * 1024 + (lane & 3) * 8;
  bf16* lA = As + w * 1024;
  bf16* lB = Bs + w * 1024;

  for (int k0 = 0; k0 < 1024; k0 += 32) {
    __syncthreads();
    gload16(gA, lA);               gload16(gA + 16 * 1024, lA + 512);
    gload16(gB, lB);               gload16(gB + 16 * 1024, lB + 512);
    gA += 32; gB += 32;
    __syncthreads();

    bf16x8 af[4], bfr[4];
#pragma unroll
    for (int mi = 0; mi < 4; ++mi)
      af[mi] = *(const bf16x8*)(As + (wr * 64 + mi * 16 + c) * 32 + g * 8);
#pragma unroll
    for (int ni = 0; ni < 4; ++ni)
      bfr[ni] = *(const bf16x8*)(Bs + (wc * 64 + ni * 16 + c) * 32 + g * 8);
#pragma unroll
    for (int mi = 0; mi < 4; ++mi)
#pragma unroll
      for (int ni = 0; ni < 4; ++ni)
        acc[mi][ni] = mfma16(af[mi], bfr[ni], acc[mi][ni]);
  }

  // C/D layout: col = lane&15, row = (lane>>4)*4 + reg  (m89-verified)
  if (EPI == 1) {
#pragma unroll
    for (int mi = 0; mi < 4; ++mi)
#pragma unroll
      for (int ni = 0; ni < 4; ++ni)
#pragma unroll
        for (int r = 0; r < 4; ++r) {
          int m = m0 + wr * 64 + mi * 16 + g * 4 + r;
          int n = n0 + wc * 64 + ni * 16 + c;
          Of[(size_t)m * 1024 + n] = acc[mi][ni][r];
        }
  } else if (z < 2) {
    // Q or K with fused RoPE: even/odd head-dim pairs are adjacent lanes
    const float2* cs = (z == 0) ? csq : cskv;
    bf16* Out = (z == 0) ? Qb : Kb;
#pragma unroll
    for (int mi = 0; mi < 4; ++mi)
#pragma unroll
      for (int ni = 0; ni < 4; ++ni)
#pragma unroll
        for (int r = 0; r < 4; ++r) {
          int m = m0 + wr * 64 + mi * 16 + g * 4 + r;
          int n = n0 + wc * 64 + ni * 16 + c;
          float v = acc[mi][ni][r];
          float p = __shfl_xor(v, 1);          // partner in the rope pair
          int t = m & 2047, b = m >> 11;
          int h = n >> 6, d = n & 63;
          float2 cv = cs[t * 32 + (d >> 1)];
          float rot = (d & 1) ? (v * cv.x + p * cv.y)    // odd:  xe*sin + xo*cos
                              : (v * cv.x - p * cv.y);   // even: xe*cos - xo*sin
          Out[((size_t)((b * 16 + h) * 2048 + t)) * 64 + d] = (bf16)rot;
        }
  } else {
    // V^T: [bh][d=64][s=2048], columns kappa-permuted within each 64-tile so
    // attention's PV B-fragment (P) is lane-local:
    //   kappa = (st>>1)*32 + q4*8 + (st&1)*4 + r2   for s-local p = st*16+q4*4+r2
#pragma unroll
    for (int mi = 0; mi < 4; ++mi)
#pragma unroll
      for (int ni = 0; ni < 4; ++ni) {
        int m = m0 + wr * 64 + mi * 16 + g * 4;   // 4 consecutive s (regs)
        int n = n0 + wc * 64 + ni * 16 + c;
        int b = m >> 11, sl = m & 2047;
        int h = n >> 6, d = n & 63;
        int p  = sl & 63;
        int st = p >> 4, q4 = (p >> 2) & 3;
        int col = (sl & ~63) | ((st >> 1) << 5) | (q4 << 3) | ((st & 1) << 2);
        bf16x4 pk = {(bf16)acc[mi][ni][0], (bf16)acc[mi][ni][1],
                     (bf16)acc[mi][ni][2], (bf16)acc[mi][ni][3]};
        *(bf16x4*)(Vtb + ((size_t)((b * 16 + h) * 64 + d)) * 2048 + col) = pk;
      }
  }
}

// ---------------------------------------------------------------------------
// Flash attention, swapped-operand form (m214-style, 16x16 MFMA):
//   QK^T computed as mfma(K,Q) -> S^T: each lane owns ONE q-row (t = lane&15)
//     -> row max/sum are in-lane chains + 2 shuffles (xor 16,32).
//   PV computed as mfma(V^T, P^T) -> D[d][t]: softmax state stays lane-local.
//   P never touches LDS: the k-slot->s permutation sigma is absorbed into
//     Vtb's column order (see k_gemm epilogue), making each lane's 16
//     register P values exactly its PV B-fragment.
//   V row 64 = ones -> PV also accumulates the softmax denominator (o[4]).
//   Defer-max (THR=8): skip o-rescale when row max doesn't grow.
// ---------------------------------------------------------------------------
__global__ __launch_bounds__(256) void k_attn(
    const bf16* __restrict__ Qb, const bf16* __restrict__ Kb,
    const bf16* __restrict__ Vtb, const float* __restrict__ bias,
    bf16* __restrict__ Ob)
{
  __shared__ bf16 Ks[64 * 64];
  __shared__ bf16 Vs[80 * 64];     // rows 0..63: V^T (kappa cols); 64: ones; 65..79: zeros
  const int bh = blockIdx.y, b = bh >> 4, h = bh & 15;
  const int t0 = blockIdx.x * 64;
  const int tid = threadIdx.x, lane = tid & 63, w = tid >> 6;
  const int g = lane >> 4, c = lane & 15;

  // init ones/zeros rows (once; visible after first loop barrier)
  {
    int rr = tid >> 4;               // 0..15 -> row 64+rr
    int col4 = (tid & 15) * 4;
    bf16 v = (rr == 0) ? (bf16)1.0f : (bf16)0.0f;
    bf16x4 vv = {v, v, v, v};
    *(bf16x4*)(Vs + (64 + rr) * 64 + col4) = vv;
  }

  // Q fragments (B-operand: col = lane&15 -> q-row t, k = (lane>>4)*8 + i)
  bf16x8 qf[2];
  {
    const bf16* qp = Qb + ((size_t)bh * 2048 + t0 + w * 16 + c) * 64;
    qf[0] = *(const bf16x8*)(qp + g * 8);
    qf[1] = *(const bf16x8*)(qp + 32 + g * 8);
  }

  float mrun = -3.0e38f;
  f32x4 o[5];
#pragma unroll
  for (int ni = 0; ni < 5; ++ni) o[ni] = 0.0f;

  // staging addresses (pre-swizzled source column, T2/m173 pattern)
  const int srow8 = lane >> 3;                     // row within 8-row chunk
  const int scol  = ((lane & 7) ^ srow8) * 8;      // inverse-swizzled elem off
  const bf16* gK = Kb  + ((size_t)bh * 2048 + w * 16 + srow8) * 64 + scol;
  const bf16* gV = Vtb + ((size_t)bh * 64 + w * 16 + srow8) * 2048 + scol;
  bf16* lK = Ks + w * 1024;
  bf16* lV = Vs + w * 1024;
  const float* bp = bias + b * 2048 + g * 4;

  for (int s0 = 0; s0 < 2048; s0 += 64) {
    __syncthreads();
    gload16(gK, lK);            gload16(gK + 512,      lK + 512);
    gload16(gV, lV);            gload16(gV + 8 * 2048, lV + 512);
    gK += 64 * 64; gV += 64;
    // bias slice for this tile (L2-resident, issued early; r-component = reg)
    float4 bv0 = *(const float4*)(bp + s0);
    float4 bv1 = *(const float4*)(bp + s0 + 16);
    float4 bv2 = *(const float4*)(bp + s0 + 32);
    float4 bv3 = *(const float4*)(bp + s0 + 48);
    __syncthreads();

    // ---- QK^T swapped: S^T[s][t], A = K rows s, B = Q cols t
    f32x4 sc[4];
#pragma unroll
    for (int st = 0; st < 4; ++st) sc[st] = 0.0f;
#pragma unroll
    for (int kd = 0; kd < 2; ++kd)
#pragma unroll
      for (int st = 0; st < 4; ++st) {
        int srow = st * 16 + c;
        bf16x8 kf = *(const bf16x8*)(Ks + srow * 64 + ((kd * 4 + g) ^ (srow & 7)) * 8);
        sc[st] = mfma16(kf, qf[kd], sc[st]);
      }

    // ---- scale + mask-bias; lane holds S[t=c][s = st*16 + g*4 + r]
    float sv[4][4];
#pragma unroll
    for (int r = 0; r < 4; ++r) {
      sv[0][r] = sc[0][r] * SCL + ((const float*)&bv0)[r];
      sv[1][r] = sc[1][r] * SCL + ((const float*)&bv1)[r];
      sv[2][r] = sc[2][r] * SCL + ((const float*)&bv2)[r];
      sv[3][r] = sc[3][r] * SCL + ((const float*)&bv3)[r];
    }

    // ---- row max: in-lane chain + 2 cross-g shuffles
    float mt = sv[0][0];
#pragma unroll
    for (int st = 0; st < 4; ++st)
#pragma unroll
      for (int r = 0; r < 4; ++r) mt = fmaxf(mt, sv[st][r]);
    mt = fmaxf(mt, __shfl_xor(mt, 16));
    mt = fmaxf(mt, __shfl_xor(mt, 32));

    // ---- defer-max (THR=8): rescale only when the row max grows
    if (__any(mt > mrun + 8.0f)) {
      float mnew = fmaxf(mrun, mt);
      float corr = exp2f(mrun - mnew);
      mrun = mnew;
#pragma unroll
      for (int ni = 0; ni < 5; ++ni) o[ni] *= corr;
    }

    // ---- P = exp2(sv - m), packed straight into PV B-fragments (lane-local)
    bf16x8 pf[2];
#pragma unroll
    for (int ks = 0; ks < 2; ++ks)
#pragma unroll
      for (int st2 = 0; st2 < 2; ++st2) {
        int st = ks * 2 + st2;
#pragma unroll
        for (int r = 0; r < 4; ++r)
          pf[ks][st2 * 4 + r] = (bf16)exp2f(sv[st][r] - mrun);
      }

    // ---- PV swapped: D[d][t], A = V^T rows d (kappa cols), B = P^T cols t
#pragma unroll
    for (int ks = 0; ks < 2; ++ks)
#pragma unroll
      for (int ni = 0; ni < 5; ++ni) {
        int vrow = ni * 16 + c;
        bf16x8 vf = *(const bf16x8*)(Vs + vrow * 64 + (((ks * 4 + g) ^ (vrow & 7)) * 8));
        o[ni] = mfma16(vf, pf[ks], o[ni]);
      }
  }

  // epilogue: l = ones-row accumulator (subtile 4, row 0 -> lanes g=0, reg 0)
  float l = __shfl(o[4][0], c);          // broadcast l(t=c) from lane c
  float rl = 1.0f / l;
  int t = t0 + w * 16 + c;
#pragma unroll
  for (int ni = 0; ni < 4; ++ni) {
    bf16x4 ov = {(bf16)(o[ni][0] * rl), (bf16)(o[ni][1] * rl),
                 (bf16)(o[ni][2] * rl), (bf16)(o[ni][3] * rl)};
    *(bf16x4*)(Ob + ((size_t)(b * 2048 + t)) * 1024 + h * 64 + ni * 16 + g * 4) = ov;
  }
}

// ---------------------------------------------------------------------------
extern "C" void kernel_launch(void* const* d_in, const int* in_sizes, int n_in,
                              void* d_out, int out_size, void* d_ws, size_t ws_size,
                              hipStream_t stream)
{
  const float* qx  = (const float*)d_in[0];
  const float* kvx = (const float*)d_in[1];
  const float* fq  = (const float*)d_in[2];
  const float* fkv = (const float*)d_in[3];
  const int*  mask = (const int*)  d_in[4];
  const float* Wq  = (const float*)d_in[5];
  const float* Wk  = (const float*)d_in[6];
  const float* Wv  = (const float*)d_in[7];
  const float* Wp  = (const float*)d_in[8];

  char* ws = (char*)d_ws;
  bf16*   wbf   = (bf16*)(ws);                    //  8 MB: [Wq|Wk|Wv|Wproj] bf16
  bf16*   qxbf  = (bf16*)(ws + 8388608);          // 16 MB
  bf16*   kvxbf = (bf16*)(ws + 25165824);         // 16 MB
  bf16*   Qb    = (bf16*)(ws + 41943040);         // 16 MB  [bh][t][64]
  bf16*   Kb    = (bf16*)(ws + 58720256);         // 16 MB  [bh][s][64]
  bf16*   Vtb   = (bf16*)(ws + 75497472);         // 16 MB  [bh][64][s] (kappa)
  bf16*   Ob    = (bf16*)(ws + 92274688);         // 16 MB  [b][t][1024]
  float2* csq   = (float2*)(ws + 109051904);      // 512 KB
  float2* cskv  = (float2*)(ws + 109576192);      // 512 KB
  float*  bias  = (float*)(ws + 110100480);       //  32 KB
  float*  out   = (float*)d_out;

  k_convert<<<4096, 256, 0, stream>>>(qx, kvx, Wq, Wk, Wv, Wp, wbf, qxbf, kvxbf);
  k_tables<<<544, 256, 0, stream>>>(fq, fkv, mask, csq, cskv, bias);
  k_gemm<0><<<dim3(64, 8, 3), 256, 0, stream>>>(qxbf, kvxbf, wbf,
                                                Qb, Kb, Vtb, nullptr, csq, cskv);
  k_attn<<<dim3(32, 64), 256, 0, stream>>>(Qb, Kb, Vtb, bias, Ob);
  k_gemm<1><<<dim3(64, 8, 1), 256, 0, stream>>>(Ob, nullptr, wbf + 3 * 1048576,
                                                nullptr, nullptr, nullptr, out, csq, cskv);
}